// Round 2
// baseline (1059.218 us; speedup 1.0000x reference)
//
#include <hip/hip_runtime.h>
#include <math.h>

#define D 64
#define WAVE 64

// ---------- wave helpers ----------
__device__ __forceinline__ float wave_reduce_sum(float v) {
    v += __shfl_xor(v, 32);
    v += __shfl_xor(v, 16);
    v += __shfl_xor(v, 8);
    v += __shfl_xor(v, 4);
    v += __shfl_xor(v, 2);
    v += __shfl_xor(v, 1);
    return v;
}

__device__ __forceinline__ float wave_reduce_max(float v) {
    v = fmaxf(v, __shfl_xor(v, 32));
    v = fmaxf(v, __shfl_xor(v, 16));
    v = fmaxf(v, __shfl_xor(v, 8));
    v = fmaxf(v, __shfl_xor(v, 4));
    v = fmaxf(v, __shfl_xor(v, 2));
    v = fmaxf(v, __shfl_xor(v, 1));
    return v;
}

__device__ __forceinline__ float fast_tanh(float x) {
    // tanh(x) = 1 - 2/(exp(2x)+1); saturates correctly at +-1 (inf-safe)
    float e = __expf(2.0f * x);
    return 1.0f - 2.0f / (e + 1.0f);
}

// ---------- 1. proj[n][r][o] = sum_i nfeat[n][i] * W[r][i][o] ----------
// Lane o holds W_r[:,o] in 64 VGPRs; nfeat row read as wave-uniform scalar
// loads (n readfirstlane'd -> s_load). 4 accumulators break the 4-cy FMA
// latency chain (64 dependent FMAs = 256cy; 4 chains -> ~128cy issue-bound).
__global__ __launch_bounds__(256) void proj_kernel(
    const float* __restrict__ nfeat, const float* __restrict__ W,
    float* __restrict__ proj, int n_nodes, int n_rel, int nodes_per_block) {
    const int lane = threadIdx.x & 63;
    const int wid = __builtin_amdgcn_readfirstlane(threadIdx.x >> 6);
    const int r = blockIdx.y;

    float w[D];
    const float* Wr = W + (size_t)r * D * D;
#pragma unroll
    for (int i = 0; i < D; ++i) w[i] = Wr[i * D + lane];  // coalesced 256B rows

    int n0 = blockIdx.x * nodes_per_block;
    int n1 = n0 + nodes_per_block;
    if (n1 > n_nodes) n1 = n_nodes;
    for (int n = n0 + wid; n < n1; n += 4) {
        const int nn = __builtin_amdgcn_readfirstlane(n);
        const float* __restrict__ x = nfeat + (size_t)nn * D;  // uniform -> s_load
        float a0 = 0.0f, a1 = 0.0f, a2 = 0.0f, a3 = 0.0f;
#pragma unroll
        for (int i = 0; i < D; i += 4) {
            a0 = fmaf(x[i + 0], w[i + 0], a0);
            a1 = fmaf(x[i + 1], w[i + 1], a1);
            a2 = fmaf(x[i + 2], w[i + 2], a2);
            a3 = fmaf(x[i + 3], w[i + 3], a3);
        }
        proj[((size_t)nn * n_rel + r) * D + lane] = (a0 + a1) + (a2 + a3);
    }
}

// ---------- 2a. att[e] = sum_d t_r[d] * tanh(h_r[d] + efeat[e][d]) ----------
// Primary path: gather precomputed proj rows. Wave per edge, lane per channel.
__global__ __launch_bounds__(256) void att_kernel(
    const float* __restrict__ proj, const float* __restrict__ efeat,
    const int* __restrict__ src, const int* __restrict__ dst,
    const int* __restrict__ etype, float* __restrict__ att,
    int n_edges, int n_rel) {
    const int lane = threadIdx.x & 63;
    const int wid = __builtin_amdgcn_readfirstlane(threadIdx.x >> 6);
    const int e = blockIdx.x * 4 + wid;
    if (e >= n_edges) return;
    const int s = src[e];      // uniform -> s_load
    const int d = dst[e];
    const int et = etype[e];
    float t = proj[((size_t)s * n_rel + et) * D + lane];
    float h = proj[((size_t)d * n_rel + et) * D + lane];
    float ef = efeat[(size_t)e * D + lane];
    float v = t * fast_tanh(h + ef);
    v = wave_reduce_sum(v);
    if (lane == 0) att[e] = v;
}

// ---------- 2b. fallback: per-edge direct matvec, W rows from L2 ----------
// Used only when ws_size can't hold proj (needs just att+rowptr scratch).
// L2-BW bound (~16KB W reads/edge) -> ~4x slower than primary, but correct.
__global__ __launch_bounds__(256) void att_direct_kernel(
    const float* __restrict__ nfeat, const float* __restrict__ efeat,
    const float* __restrict__ W,
    const int* __restrict__ src, const int* __restrict__ dst,
    const int* __restrict__ etype, float* __restrict__ att,
    int n_edges) {
    const int lane = threadIdx.x & 63;
    const int wid = __builtin_amdgcn_readfirstlane(threadIdx.x >> 6);
    const int e = blockIdx.x * 4 + wid;
    if (e >= n_edges) return;
    const int s = src[e];
    const int d = dst[e];
    const int et = etype[e];
    const float* __restrict__ xs = nfeat + (size_t)s * D;  // uniform -> s_load
    const float* __restrict__ xd = nfeat + (size_t)d * D;
    const float* __restrict__ Wr = W + (size_t)et * D * D;
    float t0 = 0.0f, t1 = 0.0f, h0 = 0.0f, h1 = 0.0f;
#pragma unroll 8
    for (int i = 0; i < D; i += 2) {
        float w0 = Wr[(i + 0) * D + lane];
        float w1 = Wr[(i + 1) * D + lane];
        t0 = fmaf(xs[i + 0], w0, t0);
        h0 = fmaf(xd[i + 0], w0, h0);
        t1 = fmaf(xs[i + 1], w1, t1);
        h1 = fmaf(xd[i + 1], w1, h1);
    }
    float ef = efeat[(size_t)e * D + lane];
    float v = (t0 + t1) * fast_tanh((h0 + h1) + ef);
    v = wave_reduce_sum(v);
    if (lane == 0) att[e] = v;
}

// ---------- 3. CSR row_ptr from sorted dst ----------
__global__ void rowptr_kernel(const int* __restrict__ dst, int* __restrict__ row_ptr,
                              int n_edges, int n_nodes) {
    int tid = blockIdx.x * blockDim.x + threadIdx.x;
    int stride = gridDim.x * blockDim.x;
    for (int e = tid; e < n_edges; e += stride) {
        int d = dst[e];
        int dprev = (e == 0) ? -1 : dst[e - 1];
        for (int v = dprev + 1; v <= d; ++v) row_ptr[v] = e;
    }
    if (tid == 0) {
        int dlast = dst[n_edges - 1];
        for (int v = dlast + 1; v <= n_nodes; ++v) row_ptr[v] = n_edges;
    }
}

// ---------- 4. fused edge-softmax + weighted aggregation ----------
// Wave per node. h_nb[n] = (sum_j ex_j * nfeat[src_j]) / (sum_j ex_j),
// ex_j = exp(att_j - max). Division factored out -> 2 passes, no a[] array.
__global__ __launch_bounds__(256) void agg_kernel(
    const float* __restrict__ att, const int* __restrict__ src,
    const int* __restrict__ row_ptr, const float* __restrict__ nfeat,
    float* __restrict__ h_nb, int n_nodes) {
    const int lane = threadIdx.x & 63;
    const int wid = __builtin_amdgcn_readfirstlane(threadIdx.x >> 6);
    const int n = blockIdx.x * 4 + wid;
    if (n >= n_nodes) return;
    const int s = row_ptr[n];
    const int t = row_ptr[n + 1];
    float acc = 0.0f;
    if (t > s) {
        // pass 1: segment max
        float m = -INFINITY;
        for (int base = s; base < t; base += WAVE) {
            int idx = base + lane;
            float a = (idx < t) ? att[idx] : -INFINITY;
            m = fmaxf(m, a);
        }
        m = wave_reduce_max(m);
        // pass 2: accumulate ex and ex-weighted src-feature rows
        float exsum = 0.0f;
        for (int base = s; base < t; base += WAVE) {
            int idx = base + lane;
            float ex = (idx < t) ? __expf(att[idx] - m) : 0.0f;
            int sv = (idx < t) ? src[idx] : 0;
            exsum += ex;
            int cnt = t - base;
            if (cnt > WAVE) cnt = WAVE;
            for (int j = 0; j < cnt; ++j) {
                float c = __shfl(ex, j);
                int sj = __shfl(sv, j);
                acc = fmaf(c, nfeat[(size_t)sj * D + lane], acc);
            }
        }
        float ssum = wave_reduce_sum(exsum);
        acc *= (1.0f / ssum);
    }
    h_nb[(size_t)n * D + lane] = acc;
}

// ---------- 5. out = lrelu((x+h)W1^T) + lrelu((x*h)W2^T) ----------
// h_nb may ALIAS out (d_out used as scratch): each wave reads row n fully
// before writing row n -> safe; no __restrict__ on h/out.
__global__ __launch_bounds__(256) void out_kernel(
    const float* __restrict__ nfeat, const float* h_nb,
    const float* __restrict__ W1, const float* __restrict__ W2,
    float* out, int n_nodes) {
    const int lane = threadIdx.x & 63;
    const int wid = __builtin_amdgcn_readfirstlane(threadIdx.x >> 6);
    float w1[D], w2[D];
#pragma unroll
    for (int i = 0; i < D; ++i) w1[i] = W1[lane * D + i];
#pragma unroll
    for (int i = 0; i < D; ++i) w2[i] = W2[lane * D + i];
    const int nwaves = gridDim.x * 4;
    for (int n = blockIdx.x * 4 + wid; n < n_nodes; n += nwaves) {
        const int nn = __builtin_amdgcn_readfirstlane(n);
        const float* x = nfeat + (size_t)nn * D;  // uniform -> s_load
        const float* h = h_nb + (size_t)nn * D;
        float a0 = 0.0f, a1 = 0.0f, b0 = 0.0f, b1 = 0.0f;
#pragma unroll
        for (int i = 0; i < D; i += 2) {
            float x0 = x[i], h0 = h[i];
            float x1 = x[i + 1], h1 = h[i + 1];
            a0 = fmaf(x0 + h0, w1[i], a0);
            b0 = fmaf(x0 * h0, w2[i], b0);
            a1 = fmaf(x1 + h1, w1[i + 1], a1);
            b1 = fmaf(x1 * h1, w2[i + 1], b1);
        }
        float a = a0 + a1, b = b0 + b1;
        a = (a > 0.0f) ? a : 0.01f * a;
        b = (b > 0.0f) ? b : 0.01f * b;
        out[(size_t)nn * D + lane] = a + b;
    }
}

// ---------- launcher ----------
extern "C" void kernel_launch(void* const* d_in, const int* in_sizes, int n_in,
                              void* d_out, int out_size, void* d_ws, size_t ws_size,
                              hipStream_t stream) {
    const float* nfeat = (const float*)d_in[0];
    const float* efeat = (const float*)d_in[1];
    const float* relw  = (const float*)d_in[2];
    const float* w1    = (const float*)d_in[3];
    const float* w2    = (const float*)d_in[4];
    const int*   src   = (const int*)d_in[5];
    const int*   dst   = (const int*)d_in[6];
    const int*   etype = (const int*)d_in[7];
    float* out = (float*)d_out;

    const int n_nodes = in_sizes[0] / D;
    const int n_edges = in_sizes[5];
    const int n_rel   = in_sizes[2] / (D * D);

    const size_t ALIGN = 256;
    const size_t proj_bytes = ((size_t)n_nodes * n_rel * D * sizeof(float) + ALIGN - 1) & ~(ALIGN - 1);
    const size_t att_bytes  = ((size_t)n_edges * sizeof(float) + ALIGN - 1) & ~(ALIGN - 1);
    const size_t rp_bytes   = ((size_t)(n_nodes + 1) * sizeof(int) + ALIGN - 1) & ~(ALIGN - 1);

    // h_nb lives in d_out (out_kernel reads row n before writing row n).
    float* h_nb = out;

    char* ws = (char*)d_ws;
    const bool use_proj = ws_size >= proj_bytes + att_bytes + rp_bytes;

    float* proj = nullptr;
    float* att;
    int* row_ptr;
    if (use_proj) {
        proj    = (float*)ws;
        att     = (float*)(ws + proj_bytes);
        row_ptr = (int*)(ws + proj_bytes + att_bytes);
    } else {
        att     = (float*)ws;
        row_ptr = (int*)(ws + att_bytes);
    }

    rowptr_kernel<<<1024, 256, 0, stream>>>(dst, row_ptr, n_edges, n_nodes);

    if (use_proj) {
        const int NODES_PER_BLOCK = 256;
        dim3 pgrid((n_nodes + NODES_PER_BLOCK - 1) / NODES_PER_BLOCK, n_rel);
        proj_kernel<<<pgrid, 256, 0, stream>>>(nfeat, relw, proj, n_nodes, n_rel, NODES_PER_BLOCK);
        att_kernel<<<(n_edges + 3) / 4, 256, 0, stream>>>(proj, efeat, src, dst, etype,
                                                          att, n_edges, n_rel);
    } else {
        att_direct_kernel<<<(n_edges + 3) / 4, 256, 0, stream>>>(nfeat, efeat, relw,
                                                                 src, dst, etype, att, n_edges);
    }

    agg_kernel<<<(n_nodes + 3) / 4, 256, 0, stream>>>(att, src, row_ptr, nfeat,
                                                      h_nb, n_nodes);

    out_kernel<<<1024, 256, 0, stream>>>(nfeat, h_nb, w1, w2, out, n_nodes);
}

// Round 3
// 846.557 us; speedup vs baseline: 1.2512x; 1.2512x over previous
//
#include <hip/hip_runtime.h>
#include <hip/hip_fp16.h>
#include <math.h>

#define D 64
#define WAVE 64

// ---------- helpers ----------
__device__ __forceinline__ float wave_reduce_sum(float v) {
    v += __shfl_xor(v, 32);
    v += __shfl_xor(v, 16);
    v += __shfl_xor(v, 8);
    v += __shfl_xor(v, 4);
    v += __shfl_xor(v, 2);
    v += __shfl_xor(v, 1);
    return v;
}

__device__ __forceinline__ float wave_reduce_max(float v) {
    v = fmaxf(v, __shfl_xor(v, 32));
    v = fmaxf(v, __shfl_xor(v, 16));
    v = fmaxf(v, __shfl_xor(v, 8));
    v = fmaxf(v, __shfl_xor(v, 4));
    v = fmaxf(v, __shfl_xor(v, 2));
    v = fmaxf(v, __shfl_xor(v, 1));
    return v;
}

__device__ __forceinline__ float fast_tanh(float x) {
    // tanh(x) = 1 - 2/(exp(2x)+1); saturates correctly at +-1 (inf-safe)
    float e = __expf(2.0f * x);
    return 1.0f - 2.0f / (e + 1.0f);
}

// ---------- 1. proj[n][r][o] = sum_i nfeat[n][i] * W[r][i][o]  (fp16 out) ----------
// Lane o holds W_r[:,o] in 64 VGPRs; nfeat row via wave-uniform s_loads.
// fp16 store: halves write traffic (128 MB) and makes proj L3-resident so
// att's random src-gathers hit Infinity Cache instead of HBM.
__global__ __launch_bounds__(256) void proj_kernel(
    const float* __restrict__ nfeat, const float* __restrict__ W,
    __half* __restrict__ proj, int n_nodes, int n_rel, int nodes_per_block) {
    const int lane = threadIdx.x & 63;
    const int wid = __builtin_amdgcn_readfirstlane(threadIdx.x >> 6);
    const int r = blockIdx.y;

    float w[D];
    const float* Wr = W + (size_t)r * D * D;
#pragma unroll
    for (int i = 0; i < D; ++i) w[i] = Wr[i * D + lane];  // coalesced 256B rows

    int n0 = blockIdx.x * nodes_per_block;
    int n1 = n0 + nodes_per_block;
    if (n1 > n_nodes) n1 = n_nodes;
    for (int n = n0 + wid; n < n1; n += 4) {
        const int nn = __builtin_amdgcn_readfirstlane(n);
        const float* __restrict__ x = nfeat + (size_t)nn * D;  // uniform -> s_load
        float a0 = 0.0f, a1 = 0.0f, a2 = 0.0f, a3 = 0.0f;
#pragma unroll
        for (int i = 0; i < D; i += 4) {
            a0 = fmaf(x[i + 0], w[i + 0], a0);
            a1 = fmaf(x[i + 1], w[i + 1], a1);
            a2 = fmaf(x[i + 2], w[i + 2], a2);
            a3 = fmaf(x[i + 3], w[i + 3], a3);
        }
        proj[((size_t)nn * n_rel + r) * D + lane] = __float2half_rn((a0 + a1) + (a2 + a3));
    }
}

// ---------- 2. att[e] = sum_d t_r[d] * tanh(h_r[d] + efeat[e][d]) ----------
// 4 edges per wave, 16 lanes per edge, 4 channels per lane:
// efeat via float4 (16B/lane), proj via 2x half2 (8B/lane), 4-step reduce.
// 4x fewer load/shuffle instructions per edge than wave-per-edge.
__global__ __launch_bounds__(256) void att_kernel(
    const __half* __restrict__ proj, const float* __restrict__ efeat,
    const int* __restrict__ src, const int* __restrict__ dst,
    const int* __restrict__ etype, float* __restrict__ att,
    int n_edges, int n_rel) {
    const int lane = threadIdx.x & 63;
    const int wid = threadIdx.x >> 6;
    const int g = lane >> 4;       // edge slot 0..3 within wave
    const int c4 = lane & 15;      // float4 chunk of the row

    int e = (blockIdx.x * 4 + wid) * 4 + g;
    const bool valid = e < n_edges;
    const int ec = valid ? e : (n_edges - 1);
    const int s = src[ec];
    const int d = dst[ec];
    const int et = etype[ec];

    const float4* ef4 = (const float4*)(efeat + (size_t)ec * D);
    float4 ef = ef4[c4];
    const __half2* tp = (const __half2*)(proj + ((size_t)s * n_rel + et) * D) + c4 * 2;
    const __half2* hp = (const __half2*)(proj + ((size_t)d * n_rel + et) * D) + c4 * 2;
    float2 tA = __half22float2(tp[0]);
    float2 tB = __half22float2(tp[1]);
    float2 hA = __half22float2(hp[0]);
    float2 hB = __half22float2(hp[1]);

    float v = tA.x * fast_tanh(hA.x + ef.x)
            + tA.y * fast_tanh(hA.y + ef.y)
            + tB.x * fast_tanh(hB.x + ef.z)
            + tB.y * fast_tanh(hB.y + ef.w);
    v += __shfl_xor(v, 8);
    v += __shfl_xor(v, 4);
    v += __shfl_xor(v, 2);
    v += __shfl_xor(v, 1);
    if (valid && c4 == 0) att[e] = v;
}

// ---------- 3. CSR row_ptr from sorted dst ----------
__global__ void rowptr_kernel(const int* __restrict__ dst, int* __restrict__ row_ptr,
                              int n_edges, int n_nodes) {
    int tid = blockIdx.x * blockDim.x + threadIdx.x;
    int stride = gridDim.x * blockDim.x;
    for (int e = tid; e < n_edges; e += stride) {
        int d = dst[e];
        int dprev = (e == 0) ? -1 : dst[e - 1];
        for (int v = dprev + 1; v <= d; ++v) row_ptr[v] = e;
    }
    if (tid == 0) {
        int dlast = dst[n_edges - 1];
        for (int v = dlast + 1; v <= n_nodes; ++v) row_ptr[v] = n_edges;
    }
}

// ---------- 4. fused edge-softmax + weighted aggregation ----------
// Wave per node. h_nb[n] = (sum_j ex_j * nfeat[src_j]) / (sum_j ex_j).
// Inner j-loop unrolled x4 with 4 acc chains + 4 gathers in flight; padded
// lanes have ex=0 so no tail guards needed (fma adds 0).
__global__ __launch_bounds__(256) void agg_kernel(
    const float* __restrict__ att, const int* __restrict__ src,
    const int* __restrict__ row_ptr, const float* __restrict__ nfeat,
    float* __restrict__ h_nb, int n_nodes) {
    const int lane = threadIdx.x & 63;
    const int wid = __builtin_amdgcn_readfirstlane(threadIdx.x >> 6);
    const int n = blockIdx.x * 4 + wid;
    if (n >= n_nodes) return;
    const int s = row_ptr[n];
    const int t = row_ptr[n + 1];
    float a0 = 0.0f, a1 = 0.0f, a2 = 0.0f, a3 = 0.0f;
    float inv = 0.0f;
    if (t > s) {
        // pass 1: segment max
        float m = -INFINITY;
        for (int base = s; base < t; base += WAVE) {
            int idx = base + lane;
            float a = (idx < t) ? att[idx] : -INFINITY;
            m = fmaxf(m, a);
        }
        m = wave_reduce_max(m);
        // pass 2: accumulate ex and ex-weighted src-feature rows
        float exsum = 0.0f;
        for (int base = s; base < t; base += WAVE) {
            int idx = base + lane;
            float ex = (idx < t) ? __expf(att[idx] - m) : 0.0f;
            int sv = (idx < t) ? src[idx] : 0;
            exsum += ex;
            int cnt = t - base;
            if (cnt > WAVE) cnt = WAVE;
            int cnt4 = (cnt + 3) & ~3;
            for (int j = 0; j < cnt4; j += 4) {
                float c0 = __shfl(ex, j + 0); int s0 = __shfl(sv, j + 0);
                float c1 = __shfl(ex, j + 1); int s1 = __shfl(sv, j + 1);
                float c2 = __shfl(ex, j + 2); int s2 = __shfl(sv, j + 2);
                float c3 = __shfl(ex, j + 3); int s3 = __shfl(sv, j + 3);
                a0 = fmaf(c0, nfeat[(size_t)s0 * D + lane], a0);
                a1 = fmaf(c1, nfeat[(size_t)s1 * D + lane], a1);
                a2 = fmaf(c2, nfeat[(size_t)s2 * D + lane], a2);
                a3 = fmaf(c3, nfeat[(size_t)s3 * D + lane], a3);
            }
        }
        float ssum = wave_reduce_sum(exsum);
        inv = 1.0f / ssum;
    }
    h_nb[(size_t)n * D + lane] = ((a0 + a1) + (a2 + a3)) * inv;
}

// ---------- 5. out = lrelu((x+h)W1^T) + lrelu((x*h)W2^T) ----------
// h_nb may ALIAS out (d_out used as scratch): each wave reads row n fully
// before writing row n -> safe; no __restrict__ on h/out.
__global__ __launch_bounds__(256) void out_kernel(
    const float* __restrict__ nfeat, const float* h_nb,
    const float* __restrict__ W1, const float* __restrict__ W2,
    float* out, int n_nodes) {
    const int lane = threadIdx.x & 63;
    const int wid = __builtin_amdgcn_readfirstlane(threadIdx.x >> 6);
    float w1[D], w2[D];
#pragma unroll
    for (int i = 0; i < D; ++i) w1[i] = W1[lane * D + i];
#pragma unroll
    for (int i = 0; i < D; ++i) w2[i] = W2[lane * D + i];
    const int nwaves = gridDim.x * 4;
    for (int n = blockIdx.x * 4 + wid; n < n_nodes; n += nwaves) {
        const int nn = __builtin_amdgcn_readfirstlane(n);
        const float* x = nfeat + (size_t)nn * D;  // uniform -> s_load
        const float* h = h_nb + (size_t)nn * D;
        float a0 = 0.0f, a1 = 0.0f, b0 = 0.0f, b1 = 0.0f;
#pragma unroll
        for (int i = 0; i < D; i += 2) {
            float x0 = x[i], h0 = h[i];
            float x1 = x[i + 1], h1 = h[i + 1];
            a0 = fmaf(x0 + h0, w1[i], a0);
            b0 = fmaf(x0 * h0, w2[i], b0);
            a1 = fmaf(x1 + h1, w1[i + 1], a1);
            b1 = fmaf(x1 * h1, w2[i + 1], b1);
        }
        float a = a0 + a1, b = b0 + b1;
        a = (a > 0.0f) ? a : 0.01f * a;
        b = (b > 0.0f) ? b : 0.01f * b;
        out[(size_t)nn * D + lane] = a + b;
    }
}

// ---------- launcher ----------
extern "C" void kernel_launch(void* const* d_in, const int* in_sizes, int n_in,
                              void* d_out, int out_size, void* d_ws, size_t ws_size,
                              hipStream_t stream) {
    const float* nfeat = (const float*)d_in[0];
    const float* efeat = (const float*)d_in[1];
    const float* relw  = (const float*)d_in[2];
    const float* w1    = (const float*)d_in[3];
    const float* w2    = (const float*)d_in[4];
    const int*   src   = (const int*)d_in[5];
    const int*   dst   = (const int*)d_in[6];
    const int*   etype = (const int*)d_in[7];
    float* out = (float*)d_out;

    const int n_nodes = in_sizes[0] / D;
    const int n_edges = in_sizes[5];
    const int n_rel   = in_sizes[2] / (D * D);

    const size_t ALIGN = 256;
    const size_t proj_bytes = ((size_t)n_nodes * n_rel * D * sizeof(__half) + ALIGN - 1) & ~(ALIGN - 1);
    const size_t att_bytes  = ((size_t)n_edges * sizeof(float) + ALIGN - 1) & ~(ALIGN - 1);

    // h_nb lives in d_out (out_kernel reads row n before writing row n).
    float* h_nb = out;

    char* ws = (char*)d_ws;
    __half* proj  = (__half*)ws;
    float* att    = (float*)(ws + proj_bytes);
    int* row_ptr  = (int*)(ws + proj_bytes + att_bytes);

    rowptr_kernel<<<1024, 256, 0, stream>>>(dst, row_ptr, n_edges, n_nodes);

    const int NODES_PER_BLOCK = 256;
    dim3 pgrid((n_nodes + NODES_PER_BLOCK - 1) / NODES_PER_BLOCK, n_rel);
    proj_kernel<<<pgrid, 256, 0, stream>>>(nfeat, relw, proj, n_nodes, n_rel, NODES_PER_BLOCK);

    // 16 edges per block (4 waves x 4 edges)
    att_kernel<<<(n_edges + 15) / 16, 256, 0, stream>>>(proj, efeat, src, dst, etype,
                                                        att, n_edges, n_rel);

    agg_kernel<<<(n_nodes + 3) / 4, 256, 0, stream>>>(att, src, row_ptr, nfeat,
                                                      h_nb, n_nodes);

    out_kernel<<<1024, 256, 0, stream>>>(nfeat, h_nb, w1, w2, out, n_nodes);
}